// Round 2
// baseline (1258.860 us; speedup 1.0000x reference)
//
#include <hip/hip_runtime.h>

// Slater-determinant ordered sampler, D=512 sites, N=128 particles.
//
// Blocked (panel) reformulation of the N x N inverse-block recursion:
//   per block of B=32 sites: S = Pb A Pb^T (32x32); run the scan on S
//   (identical rank-1 recursion, register-resident in ONE wave, no barriers);
//   then A += (V U) D^-1 (V U)^T with V = A Pb^T, U unit-upper-triangular
//   built from the scan pivots. Decisions depend only on S -> the big GEMM
//   work (V, W=VU, A-update) is fully parallel across all 8 waves.
//
// A layout: wave v owns cols [16v,16v+16); lane l owns rows {l, l+64}.

#define DD 512
#define NN 128
#define BB 32
#define NTH 512
#define TINYF 1e-30f

__global__ __launch_bounds__(NTH) void slater_blk_kernel(
    const float* __restrict__ P, const float* __restrict__ u,
    float* __restrict__ out) {
  const int tid  = threadIdx.x;
  const int wave = tid >> 6;
  const int lane = tid & 63;
  const int c0   = wave << 4;

  __shared__ float slab[4][128][8];   // 16 KB  V partial slabs (wave-pairs)
  __shared__ float Vrow[128][33];     // 16.9 KB  V row-major (pad 33)
  __shared__ float PbTW[128][36];     // 18 KB  PbT (c-major); W overlays later
  __shared__ float Smat[32][36];      // 4.6 KB  S
  __shared__ float Umat[32][36];      // 4.6 KB  U
  __shared__ float invpSh[32];
  __shared__ int   kSh;

  // u staged into registers (runtime-lane shfl during scan).
  const float u_lo = u[lane];
  const float u_hi = u[lane + 64];

  // Zero cond_probs region (harness poisons d_out).
  {
    float4 z = make_float4(0.f, 0.f, 0.f, 0.f);
    float4* o4 = (float4*)out;
#pragma unroll
    for (int j = 0; j < 32; ++j) o4[tid + j * NTH] = z;
  }

  // A = I_N distributed into registers.
  float A0[16], A1[16];
#pragma unroll
  for (int j = 0; j < 16; ++j) {
    A0[j] = (lane == c0 + j) ? 1.0f : 0.0f;
    A1[j] = (lane + 64 == c0 + j) ? 1.0f : 0.0f;
  }

  // Scan state (only wave 0's copy is live across blocks).
  float ratio = 1.0f, cumul = 0.0f;
  int k = 0;

  __syncthreads();  // zero-init + LDS ready

  for (int blk = 0; blk < DD / BB; ++blk) {
    const int i0 = blk * BB;

    // ---- stage PbT[c][t] = P[i0+t][c] ----
    {
      const int t = tid & 31, cb = (tid >> 5) * 8;
      const float* src = P + (i0 + t) * NN + cb;
      float4 a = *(const float4*)src;
      float4 b = *(const float4*)(src + 4);
      PbTW[cb + 0][t] = a.x; PbTW[cb + 1][t] = a.y;
      PbTW[cb + 2][t] = a.z; PbTW[cb + 3][t] = a.w;
      PbTW[cb + 4][t] = b.x; PbTW[cb + 5][t] = b.y;
      PbTW[cb + 6][t] = b.z; PbTW[cb + 7][t] = b.w;
    }
    __syncthreads();  // B0

    // ---- V = A Pb^T in 4 passes of 8 t-columns; fused S partials ----
#pragma unroll 1
    for (int pass = 0; pass < 4; ++pass) {
      const int tbase = pass * 8;
      float vp0[8], vp1[8];
#pragma unroll
      for (int tt = 0; tt < 8; ++tt) { vp0[tt] = 0.f; vp1[tt] = 0.f; }
#pragma unroll
      for (int j = 0; j < 16; ++j) {
        const float a0 = A0[j], a1 = A1[j];
        const float4 pa = *(const float4*)&PbTW[c0 + j][tbase];
        const float4 pb = *(const float4*)&PbTW[c0 + j][tbase + 4];
        const float pv[8] = {pa.x, pa.y, pa.z, pa.w, pb.x, pb.y, pb.z, pb.w};
#pragma unroll
        for (int tt = 0; tt < 8; ++tt) {
          vp0[tt] = fmaf(a0, pv[tt], vp0[tt]);
          vp1[tt] = fmaf(a1, pv[tt], vp1[tt]);
        }
      }
      if (wave < 4) {
        *(float4*)&slab[wave][lane][0] = make_float4(vp0[0], vp0[1], vp0[2], vp0[3]);
        *(float4*)&slab[wave][lane][4] = make_float4(vp0[4], vp0[5], vp0[6], vp0[7]);
        *(float4*)&slab[wave][lane + 64][0] = make_float4(vp1[0], vp1[1], vp1[2], vp1[3]);
        *(float4*)&slab[wave][lane + 64][4] = make_float4(vp1[4], vp1[5], vp1[6], vp1[7]);
      }
      __syncthreads();  // B1
      if (wave >= 4) {
        const int w = wave - 4;
#pragma unroll
        for (int tt = 0; tt < 8; ++tt) {
          slab[w][lane][tt] += vp0[tt];
          slab[w][lane + 64][tt] += vp1[tt];
        }
      }
      __syncthreads();  // B2
      // reduce 4 slabs -> Vrow
      {
        const int r = tid & 127, t2 = (tid >> 7) * 2;
        float s0 = 0.f, s1 = 0.f;
#pragma unroll
        for (int v = 0; v < 4; ++v) {
          s0 += slab[v][r][t2];
          s1 += slab[v][r][t2 + 1];
        }
        Vrow[r][tbase + t2] = s0;
        Vrow[r][tbase + t2 + 1] = s1;
      }
      __syncthreads();  // B3
      // S partials: wave w owns S rows [4w,4w+4), cols [tbase,tbase+8)
      {
        float sp[32];
#pragma unroll
        for (int v = 0; v < 32; ++v) sp[v] = 0.f;
#pragma unroll
        for (int rr2 = 0; rr2 < 2; ++rr2) {
          const int rr = lane + rr2 * 64;
          float pbv[4];
#pragma unroll
          for (int dt = 0; dt < 4; ++dt) pbv[dt] = PbTW[rr][4 * wave + dt];
#pragma unroll
          for (int tp = 0; tp < 8; ++tp) {
            const float vv = Vrow[rr][tbase + tp];
#pragma unroll
            for (int dt = 0; dt < 4; ++dt)
              sp[dt * 8 + tp] = fmaf(pbv[dt], vv, sp[dt * 8 + tp]);
          }
        }
        // recursive-halving butterfly: 32 values over 64 lanes
#pragma unroll
        for (int rnd = 0; rnd < 5; ++rnd) {
          const int s = 1 << rnd;
          const int half = 16 >> rnd;
          const bool hi = (lane & s) != 0;
#pragma unroll
          for (int j = 0; j < half; ++j) {
            const float lo_v = sp[j], hi_v = sp[j + half];
            const float send = hi ? lo_v : hi_v;
            const float got = __shfl_xor(send, s, 64);
            sp[j] = (hi ? hi_v : lo_v) + got;
          }
        }
        sp[0] += __shfl_xor(sp[0], 32, 64);
        if (lane < 32) {
          const int v = ((lane & 1) << 4) | ((lane & 2) << 2) | (lane & 4) |
                        ((lane & 8) >> 2) | ((lane & 16) >> 4);
          Smat[4 * wave + (v >> 3)][tbase + (v & 7)] = sp[0];
        }
      }
    }
    __syncthreads();  // B4: Smat complete

    // ---- scan: wave 0 only, register-resident, no barriers ----
    if (wave == 0) {
      const int a = lane & 31;
      float Sreg[32], Ereg[32], Ureg[32];
#pragma unroll
      for (int j = 0; j < 32; ++j) {
        Sreg[j] = Smat[a][j];
        Ereg[j] = 0.f;
        Ureg[j] = 0.f;
      }
#pragma unroll
      for (int t = 0; t < BB; ++t) {
        const int i = i0 + t;
        const float x = Sreg[t];
        const float stt = __shfl(x, t, 64);
        const float s = 1.0f - stt;
        const int la = DD - NN + k;
        const bool active = (k < NN) && (i <= la);
        const float pr = active ? stt * ratio : 0.0f;
        const int kc = (k < NN) ? k : (NN - 1);
        const float uk =
            (kc < 64) ? __shfl(u_lo, kc, 64) : __shfl(u_hi, kc - 64, 64);
        const bool occupy = active && ((cumul + pr >= uk) || (i == la));
        float pivot = occupy ? (s - 1.0f) : s;
        pivot = (fabsf(pivot) < TINYF) ? TINYF : pivot;
        const float invp = 1.0f / pivot;
        if (lane == 0) {
          if (k < NN) out[k * DD + i] = pr;
          if (occupy) out[NN * DD + k] = (float)i;
          invpSh[t] = invp;
        }
        ratio = occupy ? 1.0f : (active ? ratio * s : ratio);
        cumul = occupy ? 0.0f : (cumul + pr);
        k += occupy ? 1 : 0;
        const float ec = x * invp;
        Ereg[t] = ec;
        // U column t: u_t[a] = sum_{m=a..t-1} U_am * E_mt
        float acc = 0.0f;
#pragma unroll
        for (int m = 0; m < t; ++m)
          acc = fmaf(Ureg[m], __shfl(Ereg[m], t, 64), acc);
        Ureg[t] = acc + ((a == t) ? 1.0f : 0.0f);
        // trailing rank-1 update of S~
        const float y = x * invp;
#pragma unroll
        for (int b = t + 1; b < BB; ++b)
          Sreg[b] = fmaf(y, __shfl(x, b, 64), Sreg[b]);
      }
      if (lane < 32) {
        float* urow = &Umat[lane][0];
#pragma unroll
        for (int j = 0; j < 8; ++j)
          *(float4*)&urow[4 * j] = make_float4(Ureg[4 * j], Ureg[4 * j + 1],
                                               Ureg[4 * j + 2], Ureg[4 * j + 3]);
      }
      if (lane == 0) kSh = k;
    }
    __syncthreads();  // B5: U, invp, k published

    const bool last = (blk == DD / BB - 1) || (kSh >= NN);
    if (last) break;  // uniform

    // ---- W = V U (into PbTW region; PbT dead) ----
    {
      const int r = tid & 127, t0 = (tid >> 7) * 8;
      float wacc[8];
#pragma unroll
      for (int tt = 0; tt < 8; ++tt) wacc[tt] = 0.f;
      for (int j = 0; j < t0 + 8; ++j) {  // U[j][t]=0 for j>t
        const float vv = Vrow[r][j];
        const float4 ua = *(const float4*)&Umat[j][t0];
        const float4 ub = *(const float4*)&Umat[j][t0 + 4];
        wacc[0] = fmaf(vv, ua.x, wacc[0]);
        wacc[1] = fmaf(vv, ua.y, wacc[1]);
        wacc[2] = fmaf(vv, ua.z, wacc[2]);
        wacc[3] = fmaf(vv, ua.w, wacc[3]);
        wacc[4] = fmaf(vv, ub.x, wacc[4]);
        wacc[5] = fmaf(vv, ub.y, wacc[5]);
        wacc[6] = fmaf(vv, ub.z, wacc[6]);
        wacc[7] = fmaf(vv, ub.w, wacc[7]);
      }
#pragma unroll
      for (int tt = 0; tt < 8; ++tt) PbTW[r][t0 + tt] = wacc[tt];
    }
    __syncthreads();  // B6: W ready

    // ---- A += W D^-1 W^T ----
    {
      float iv[32];
#pragma unroll
      for (int j = 0; j < 8; ++j) {
        const float4 q = *(const float4*)&invpSh[4 * j];
        iv[4 * j] = q.x; iv[4 * j + 1] = q.y;
        iv[4 * j + 2] = q.z; iv[4 * j + 3] = q.w;
      }
      float wr0[32], wr1[32];
#pragma unroll
      for (int t = 0; t < 32; ++t) {
        wr0[t] = PbTW[lane][t] * iv[t];
        wr1[t] = PbTW[lane + 64][t] * iv[t];
      }
#pragma unroll
      for (int j = 0; j < 16; ++j) {
        const int c = c0 + j;
        const float* wrow = &PbTW[c][0];
        float a0 = A0[j], a1 = A1[j];
#pragma unroll
        for (int t8 = 0; t8 < 8; ++t8) {
          const float4 wc = *(const float4*)&wrow[4 * t8];
          a0 = fmaf(wr0[4 * t8 + 0], wc.x, a0);
          a0 = fmaf(wr0[4 * t8 + 1], wc.y, a0);
          a0 = fmaf(wr0[4 * t8 + 2], wc.z, a0);
          a0 = fmaf(wr0[4 * t8 + 3], wc.w, a0);
          a1 = fmaf(wr1[4 * t8 + 0], wc.x, a1);
          a1 = fmaf(wr1[4 * t8 + 1], wc.y, a1);
          a1 = fmaf(wr1[4 * t8 + 2], wc.z, a1);
          a1 = fmaf(wr1[4 * t8 + 3], wc.w, a1);
        }
        A0[j] = a0;
        A1[j] = a1;
      }
    }
    __syncthreads();  // B7: protect PbTW before next block's staging
  }
}

extern "C" void kernel_launch(void* const* d_in, const int* in_sizes, int n_in,
                              void* d_out, int out_size, void* d_ws,
                              size_t ws_size, hipStream_t stream) {
  const float* P = (const float*)d_in[0];  // (512, 128) row-major fp32
  const float* u = (const float*)d_in[1];  // (128,) fp32
  float* out = (float*)d_out;              // 65536 cond_probs + 128 positions
  hipLaunchKernelGGL(slater_blk_kernel, dim3(1), dim3(NTH), 0, stream, P, u,
                     out);
}